// Round 6
// baseline (660.689 us; speedup 1.0000x reference)
//
#include <hip/hip_runtime.h>
#include <hip/hip_bf16.h>

typedef __bf16 bf16;
typedef __bf16 bf16x4 __attribute__((ext_vector_type(4)));
typedef __bf16 bf16x8 __attribute__((ext_vector_type(8)));
typedef float  f32x4  __attribute__((ext_vector_type(4)));

#define EDIM 1536
#define DDIM 128
#define CDIM 1664   // E + D
#define TM   32
#define NSTG 48     // phase A chunks: 1536 / 32

#define MFMA_B16(a, b, c) __builtin_amdgcn_mfma_f32_16x16x32_bf16((a), (b), (c), 0, 0, 0)

__device__ __forceinline__ float sigf(float x) { return 1.0f / (1.0f + __expf(-x)); }
__device__ __forceinline__ float tanhf_fast(float x) { return 2.0f / (1.0f + __expf(-2.0f * x)) - 1.0f; }

// f32 -> bf16 weight conversion into workspace
__global__ __launch_bounds__(256) void prep_convert(const float* __restrict__ w_ih,
                                                    const float* __restrict__ w_hh,
                                                    bf16* __restrict__ wib,
                                                    bf16* __restrict__ whb) {
  const int i = (blockIdx.x * 256 + threadIdx.x) * 4;
  const int TIH = 3 * DDIM * EDIM;
  const int THH = 3 * DDIM * DDIM;
  if (i < TIH) {
    const float4 v = *(const float4*)(w_ih + i);
    bf16x4 o = {(bf16)v.x, (bf16)v.y, (bf16)v.z, (bf16)v.w};
    *(bf16x4*)(wib + i) = o;
  } else if (i < TIH + THH) {
    const int j = i - TIH;
    const float4 v = *(const float4*)(w_hh + j);
    bf16x4 o = {(bf16)v.x, (bf16)v.y, (bf16)v.z, (bf16)v.w};
    *(bf16x4*)(whb + j) = o;
  }
}

// TM=32 rows, 256 thr = 4 waves; wave wn owns cols d in [32*wn,+32) of each
// gate. W (L2-resident, 1.2MB) read per-lane directly from global with
// explicit ping-pong register prefetch (wP/wQ, unroll-2) -> no W LDS, no
// W bank conflicts, no 128-reg clamp (launch_bounds(256,2)).
__global__ __launch_bounds__(256, 2) void gru_fused(
    const float* __restrict__ emb, const int* __restrict__ ids,
    const float* __restrict__ mem,
    const float* __restrict__ b_ih, const float* __restrict__ b_hh,
    const float* __restrict__ cls_w, const float* __restrict__ cls_b,
    const bf16* __restrict__ wib, const bf16* __restrict__ whb,
    float* __restrict__ logits, float* __restrict__ omem, int Nrows)
{
  __shared__ char  sA[2][2560];   // A slice dbuf: 32 rows x 80B (32 k bf16 + pad)
  __shared__ char  sP[8192];      // prev gathered: 32 rows x 256B (R3-proven swizzle)
  __shared__ float sLp[32][2];
  __shared__ int   sIds[32];

  const int t    = threadIdx.x;
  const int lane = t & 63;
  const int wn   = t >> 6;        // wave index = column group 0..3
  const int l15  = lane & 15;
  const int lq   = lane >> 4;     // 0..3
  const int m0   = blockIdx.x * TM;

  if (t < 32) sIds[t] = (m0 + t < Nrows) ? ids[m0 + t] : 0;
  if (t < 64) sLp[t >> 1][t & 1] = cls_b[t & 1];

  // accumulators, bias-initialized (r,z: b_ih+b_hh; n-gate split accN/accH)
  f32x4 accR[2][2], accZ[2][2], accN[2][2], accH[2][2];
#pragma unroll
  for (int sub = 0; sub < 2; ++sub) {
    const int nc = wn * 32 + sub * 16 + l15;
    const float br = b_ih[nc] + b_hh[nc];
    const float bz = b_ih[128 + nc] + b_hh[128 + nc];
    const float bn = b_ih[256 + nc];
    const float bh = b_hh[256 + nc];
#pragma unroll
    for (int mt = 0; mt < 2; ++mt) {
      accR[mt][sub] = (f32x4){br, br, br, br};
      accZ[mt][sub] = (f32x4){bz, bz, bz, bz};
      accN[mt][sub] = (f32x4){bn, bn, bn, bn};
      accH[mt][sub] = (f32x4){bh, bh, bh, bh};
    }
  }

  // A staging role: thread t handles row ar = t>>3, f32-quad aq = t&7
  const int  ar = t >> 3;
  const int  aq = t & 7;
  const bool av = (m0 + ar) < Nrows;
  const float* pA = emb + (size_t)(m0 + ar) * EDIM + aq * 4;
  const int  awofs = ar * 80 + aq * 8;
  float lp0 = 0.f, lp1 = 0.f;

  // per-lane W fragment base: row (wn*32 + l15), k-seg lq*8
  const bf16* pW = wib + (size_t)(wn * 32 + l15) * EDIM + lq * 8;

  bf16x8 wP[6], wQ[6];

  // frag (g,sub) row offset from pW: (g*128 + sub*16) * EDIM
#define LOADW(DST, S) do {                                    \
    const bf16* _p = pW + (size_t)(S) * 32;                   \
    DST[0] = *(const bf16x8*)(_p);                            \
    DST[1] = *(const bf16x8*)(_p +  16 * EDIM);               \
    DST[2] = *(const bf16x8*)(_p + 128 * EDIM);               \
    DST[3] = *(const bf16x8*)(_p + 144 * EDIM);               \
    DST[4] = *(const bf16x8*)(_p + 256 * EDIM);               \
    DST[5] = *(const bf16x8*)(_p + 272 * EDIM);               \
  } while (0)

#define BODY(S, CUR, WC, WNX, PF) do {                                        \
    float4 a = make_float4(0.f, 0.f, 0.f, 0.f), c0 = a, c1 = a;               \
    if (PF) {                                                                 \
      LOADW(WNX, (S) + 1);                                                    \
      if (av) a = *(const float4*)(pA + ((S) + 1) * 32);                      \
      c0 = *(const float4*)(cls_w + ((S) + 1) * 32 + aq * 4);                 \
      c1 = *(const float4*)(cls_w + CDIM + ((S) + 1) * 32 + aq * 4);          \
    }                                                                         \
    bf16x8 af0 = *(bf16x8*)(sA[CUR] + (l15) * 80 + lq * 16);                  \
    bf16x8 af1 = *(bf16x8*)(sA[CUR] + (16 + l15) * 80 + lq * 16);             \
    accR[0][0] = MFMA_B16(af0, WC[0], accR[0][0]);                            \
    accR[1][0] = MFMA_B16(af1, WC[0], accR[1][0]);                            \
    accR[0][1] = MFMA_B16(af0, WC[1], accR[0][1]);                            \
    accR[1][1] = MFMA_B16(af1, WC[1], accR[1][1]);                            \
    accZ[0][0] = MFMA_B16(af0, WC[2], accZ[0][0]);                            \
    accZ[1][0] = MFMA_B16(af1, WC[2], accZ[1][0]);                            \
    accZ[0][1] = MFMA_B16(af0, WC[3], accZ[0][1]);                            \
    accZ[1][1] = MFMA_B16(af1, WC[3], accZ[1][1]);                            \
    accN[0][0] = MFMA_B16(af0, WC[4], accN[0][0]);                            \
    accN[1][0] = MFMA_B16(af1, WC[4], accN[1][0]);                            \
    accN[0][1] = MFMA_B16(af0, WC[5], accN[0][1]);                            \
    accN[1][1] = MFMA_B16(af1, WC[5], accN[1][1]);                            \
    if (PF) {                                                                 \
      lp0 += a.x * c0.x + a.y * c0.y + a.z * c0.z + a.w * c0.w;               \
      lp1 += a.x * c1.x + a.y * c1.y + a.z * c1.z + a.w * c1.w;               \
      bf16x4 o = {(bf16)a.x, (bf16)a.y, (bf16)a.z, (bf16)a.w};                \
      *(bf16x4*)(sA[(CUR) ^ 1] + awofs) = o;                                  \
    }                                                                         \
    __syncthreads();                                                          \
  } while (0)

  // ---- prologue: W chunk 0 into wP, A slice 0 into sA[0] ----
  LOADW(wP, 0);
  {
    float4 a = make_float4(0.f, 0.f, 0.f, 0.f);
    if (av) a = *(const float4*)pA;
    const float4 c0 = *(const float4*)(cls_w + aq * 4);
    const float4 c1 = *(const float4*)(cls_w + CDIM + aq * 4);
    lp0 += a.x * c0.x + a.y * c0.y + a.z * c0.z + a.w * c0.w;
    lp1 += a.x * c1.x + a.y * c1.y + a.z * c1.z + a.w * c1.w;
    bf16x4 o = {(bf16)a.x, (bf16)a.y, (bf16)a.z, (bf16)a.w};
    *(bf16x4*)(sA[0] + awofs) = o;
  }
  __syncthreads();

  // ---- Phase A: gi over K=1536 in 48 chunks of 32, unroll-2 ping-pong ----
  for (int s = 0; s < NSTG; s += 2) {
    BODY(s, 0, wP, wQ, true);                    // even: consume wP, load wQ
    BODY(s + 1, 1, wQ, wP, (s + 2) < NSTG);      // odd: consume wQ, load wP
  }

  // classifier emb-part: reduce over the 8 threads sharing row ar
  {
    float v0 = lp0, v1 = lp1;
    v0 += __shfl_xor(v0, 1); v0 += __shfl_xor(v0, 2); v0 += __shfl_xor(v0, 4);
    v1 += __shfl_xor(v1, 1); v1 += __shfl_xor(v1, 2); v1 += __shfl_xor(v1, 4);
    if ((lane & 7) == 0) {
      atomicAdd(&sLp[ar][0], v0);
      atomicAdd(&sLp[ar][1], v1);
    }
  }

  // ---- Phase B: gather prev -> sP, gh over K=128 (direct whb L2 reads) ----
  {
    const int prow = t >> 5;            // 0..7
    const int pc   = t & 31;            // f32 quad: col = pc*4
#pragma unroll
    for (int p = 0; p < 4; ++p) {
      const int r = p * 8 + prow;
      const float4 v = *(const float4*)(mem + (size_t)sIds[r] * DDIM + pc * 4);
      bf16x4 o = {(bf16)v.x, (bf16)v.y, (bf16)v.z, (bf16)v.w};
      *(bf16x4*)(sP + r * 256 + ((pc << 3) ^ ((r & 7) << 4))) = o;
    }
  }
  __syncthreads();

#pragma unroll
  for (int ks = 0; ks < 4; ++ks) {
    bf16x8 af[2];
#pragma unroll
    for (int mt = 0; mt < 2; ++mt) {
      const int m = mt * 16 + l15;
      const int kb = (ks * 32 + lq * 8) << 1;
      af[mt] = *(bf16x8*)(sP + m * 256 + (kb ^ ((m & 7) << 4)));
    }
    const int kg = ks * 32 + lq * 8;
#pragma unroll
    for (int g = 0; g < 3; ++g) {
#pragma unroll
      for (int sub = 0; sub < 2; ++sub) {
        const int n = g * 128 + wn * 32 + sub * 16 + l15;
        const bf16x8 bfr = *(const bf16x8*)(whb + n * DDIM + kg);
        if (g == 0) {
          accR[0][sub] = MFMA_B16(af[0], bfr, accR[0][sub]);
          accR[1][sub] = MFMA_B16(af[1], bfr, accR[1][sub]);
        } else if (g == 1) {
          accZ[0][sub] = MFMA_B16(af[0], bfr, accZ[0][sub]);
          accZ[1][sub] = MFMA_B16(af[1], bfr, accZ[1][sub]);
        } else {
          accH[0][sub] = MFMA_B16(af[0], bfr, accH[0][sub]);
          accH[1][sub] = MFMA_B16(af[1], bfr, accH[1][sub]);
        }
      }
    }
  }

  // ---- Epilogue: gates, scatter new_mem, classifier mem-part ----
  float lpM[8][2];
#pragma unroll
  for (int i = 0; i < 8; ++i) { lpM[i][0] = 0.f; lpM[i][1] = 0.f; }

#pragma unroll
  for (int mt = 0; mt < 2; ++mt) {
#pragma unroll
    for (int sub = 0; sub < 2; ++sub) {
      const int d = wn * 32 + sub * 16 + l15;
      const float cw0 = cls_w[EDIM + d];
      const float cw1 = cls_w[CDIM + EDIM + d];
#pragma unroll
      for (int j = 0; j < 4; ++j) {
        const int m = mt * 16 + lq * 4 + j;
        const float r = sigf(accR[mt][sub][j]);
        const float z = sigf(accZ[mt][sub][j]);
        const float n = tanhf_fast(accN[mt][sub][j] + r * accH[mt][sub][j]);
        const float pv = mem[(size_t)sIds[m] * DDIM + d];
        const float nv = (1.0f - z) * n + z * pv;
        if (m0 + m < Nrows) omem[(size_t)sIds[m] * DDIM + d] = nv;
        lpM[mt * 4 + j][0] += nv * cw0;
        lpM[mt * 4 + j][1] += nv * cw1;
      }
    }
  }

#pragma unroll
  for (int i = 0; i < 8; ++i) {
#pragma unroll
    for (int c = 0; c < 2; ++c) {
      float v = lpM[i][c];
      v += __shfl_xor(v, 1); v += __shfl_xor(v, 2);
      v += __shfl_xor(v, 4); v += __shfl_xor(v, 8);
      if (l15 == 0) {
        const int m = (i >> 2) * 16 + lq * 4 + (i & 3);
        atomicAdd(&sLp[m][c], v);
      }
    }
  }
  __syncthreads();

  if (t < 64) {
    const int m = t >> 1, c = t & 1;
    if (m0 + m < Nrows) logits[(size_t)(m0 + m) * 2 + c] = sLp[m][c];
  }
}

extern "C" void kernel_launch(void* const* d_in, const int* in_sizes, int n_in,
                              void* d_out, int out_size, void* d_ws, size_t ws_size,
                              hipStream_t stream) {
  const float* emb   = (const float*)d_in[0];
  const int*   ids   = (const int*)d_in[1];
  const float* mem   = (const float*)d_in[2];
  const float* w_ih  = (const float*)d_in[3];
  const float* w_hh  = (const float*)d_in[4];
  const float* b_ih  = (const float*)d_in[5];
  const float* b_hh  = (const float*)d_in[6];
  const float* cls_w = (const float*)d_in[7];
  const float* cls_b = (const float*)d_in[8];

  const int N    = in_sizes[0] / EDIM;   // 100000
  const int MAXN = in_sizes[2] / DDIM;   // 250000

  float* logits = (float*)d_out;
  float* omem   = (float*)d_out + (size_t)N * 2;
  bf16*  wib    = (bf16*)d_ws;
  bf16*  whb    = wib + 3 * DDIM * EDIM;

  // 1) blanket copy memory -> out (scatter below overwrites active rows)
  hipMemcpyAsync(omem, mem, (size_t)MAXN * DDIM * sizeof(float),
                 hipMemcpyDeviceToDevice, stream);
  // 2) weights to bf16
  const int prep_threads = (3 * DDIM * EDIM + 3 * DDIM * DDIM) / 4;
  prep_convert<<<(prep_threads + 255) / 256, 256, 0, stream>>>(w_ih, w_hh, wib, whb);
  // 3) fused GRU + classifier
  gru_fused<<<(N + TM - 1) / TM, 256, 0, stream>>>(emb, ids, mem, b_ih, b_hh,
                                                   cls_w, cls_b, wib, whb,
                                                   logits, omem, N);
}

// Round 7
// 517.517 us; speedup vs baseline: 1.2767x; 1.2767x over previous
//
#include <hip/hip_runtime.h>
#include <hip/hip_bf16.h>

typedef __bf16 bf16;
typedef __bf16 bf16x4 __attribute__((ext_vector_type(4)));
typedef __bf16 bf16x8 __attribute__((ext_vector_type(8)));
typedef float  f32x4  __attribute__((ext_vector_type(4)));

#define EDIM 1536
#define DDIM 128
#define CDIM 1664   // E + D
#define TM   64
#define NCH  48     // phase A chunks: 1536 / 32

#define MFMA_B16(a, b, c) __builtin_amdgcn_mfma_f32_16x16x32_bf16((a), (b), (c), 0, 0, 0)

__device__ __forceinline__ float sigf(float x) { return 1.0f / (1.0f + __expf(-x)); }
__device__ __forceinline__ float tanhf_fast(float x) { return 2.0f / (1.0f + __expf(-2.0f * x)) - 1.0f; }

__device__ __forceinline__ void glds16(const void* g, void* l) {
  __builtin_amdgcn_global_load_lds(
      (const __attribute__((address_space(1))) unsigned int*)g,
      (__attribute__((address_space(3))) unsigned int*)l, 16, 0, 0);
}

// Stage one 384x32 bf16 weight chunk (24 KB) into LDS. Dest is LINEAR
// (wave-uniform base + lane*16, same mechanism R4 proved correct); only the
// per-lane SOURCE decode changes: slot s holds row (s>>6)*16 + (s&15),
// k-seg (s>>4)&3.  B-frag read then = base + lane*16 (0-way bank conflict).
template <int LDA>
__device__ __forceinline__ void stageW(const bf16* __restrict__ w, int k0,
                                       char* dst, int wave, int lane) {
#pragma unroll
  for (int j = 0; j < 3; ++j) {
    const int segbase = j * 512 + wave * 64;     // wave-uniform
    const int s = segbase + lane;                // 0..1535
    const int n = ((s >> 6) << 4) + (s & 15);    // row 0..383 (k-outer/row-inner)
    const int q = (s >> 4) & 3;                  // 16B k-seg within chunk
    glds16(w + (size_t)n * LDA + k0 + q * 8, dst + (size_t)segbase * 16);
  }
}

// f32 -> bf16 weight conversion into workspace
__global__ __launch_bounds__(256) void prep_convert(const float* __restrict__ w_ih,
                                                    const float* __restrict__ w_hh,
                                                    bf16* __restrict__ wib,
                                                    bf16* __restrict__ whb) {
  const int i = (blockIdx.x * 256 + threadIdx.x) * 4;
  const int TIH = 3 * DDIM * EDIM;
  const int THH = 3 * DDIM * DDIM;
  if (i < TIH) {
    const float4 v = *(const float4*)(w_ih + i);
    bf16x4 o = {(bf16)v.x, (bf16)v.y, (bf16)v.z, (bf16)v.w};
    *(bf16x4*)(wib + i) = o;
  } else if (i < TIH + THH) {
    const int j = i - TIH;
    const float4 v = *(const float4*)(w_hh + j);
    bf16x4 o = {(bf16)v.x, (bf16)v.y, (bf16)v.z, (bf16)v.w};
    *(bf16x4*)(whb + j) = o;
  }
}

// TM=64 rows, 512 thr = 8 waves (wm 0..1 rows, wn 0..3 gate-aligned cols).
// W chunks prefetched into LDS dbuf via global_load_lds (no regs held),
// one barrier per 32-k chunk. R4 skeleton; only W slot permutation changed.
__global__ __launch_bounds__(512, 4) void gru_fused(
    const float* __restrict__ emb, const int* __restrict__ ids,
    const float* __restrict__ mem,
    const float* __restrict__ b_ih, const float* __restrict__ b_hh,
    const float* __restrict__ cls_w, const float* __restrict__ cls_b,
    const bf16* __restrict__ wib, const bf16* __restrict__ whb,
    float* __restrict__ logits, float* __restrict__ omem, int Nrows)
{
  __shared__ char  sW[2][24576];  // W chunk dbuf: 24 groups x [4 segs][16 rows][16B]
  __shared__ char  sA[2][5120];   // A slice dbuf: 64 rows x 80B (32 k bf16 + pad)
  __shared__ char  sP[16384];     // prev gathered: 64 rows x 256B (proven swizzle)
  __shared__ float sLp[64][2];
  __shared__ int   sIds[64];

  const int t    = threadIdx.x;
  const int lane = t & 63;
  const int wave = t >> 6;
  const int wm   = wave >> 2;     // 0..1
  const int wn   = wave & 3;      // 0..3
  const int l15  = lane & 15;
  const int lq   = lane >> 4;     // 0..3
  const int m0   = blockIdx.x * TM;

  if (t < 64)  sIds[t] = (m0 + t < Nrows) ? ids[m0 + t] : 0;
  if (t < 128) sLp[t >> 1][t & 1] = cls_b[t & 1];

  // accumulators, bias-initialized (r,z: b_ih+b_hh; n-gate split accN/accH)
  f32x4 accR[2][2], accZ[2][2], accN[2][2], accH[2][2];
#pragma unroll
  for (int sub = 0; sub < 2; ++sub) {
    const int nc = wn * 32 + sub * 16 + l15;
    const float br = b_ih[nc] + b_hh[nc];
    const float bz = b_ih[128 + nc] + b_hh[128 + nc];
    const float bn = b_ih[256 + nc];
    const float bh = b_hh[256 + nc];
#pragma unroll
    for (int mt = 0; mt < 2; ++mt) {
      accR[mt][sub] = (f32x4){br, br, br, br};
      accZ[mt][sub] = (f32x4){bz, bz, bz, bz};
      accN[mt][sub] = (f32x4){bn, bn, bn, bn};
      accH[mt][sub] = (f32x4){bh, bh, bh, bh};
    }
  }

  // per-thread W read base: group (wn*2) + lane*16 within each 1KB group
  const int wrd = (wn << 11) + (lq << 8) + (l15 << 4);
  // frag (g,sub) adds ((g*8 + sub) << 10)

  // A staging role: thread t handles row ar = t>>3, f32-quad aq = t&7
  const int  ar = t >> 3;
  const int  aq = t & 7;
  const bool av = (m0 + ar) < Nrows;
  const float* pA = emb + (size_t)(m0 + ar) * EDIM + aq * 4;
  const int  awofs = ar * 80 + aq * 8;   // bf16x4 (8B) dest within A slice
  float lp0 = 0.f, lp1 = 0.f;

  // ---- prologue: stage chunk 0 (W via glds, A via reg+cvt) ----
  stageW<EDIM>(wib, 0, sW[0], wave, lane);
  {
    float4 a = make_float4(0.f, 0.f, 0.f, 0.f);
    if (av) a = *(const float4*)pA;
    const float4 c0 = *(const float4*)(cls_w + aq * 4);
    const float4 c1 = *(const float4*)(cls_w + CDIM + aq * 4);
    lp0 += a.x * c0.x + a.y * c0.y + a.z * c0.z + a.w * c0.w;
    lp1 += a.x * c1.x + a.y * c1.y + a.z * c1.z + a.w * c1.w;
    bf16x4 o = {(bf16)a.x, (bf16)a.y, (bf16)a.z, (bf16)a.w};
    *(bf16x4*)(sA[0] + awofs) = o;
  }
  __syncthreads();

  // ---- Phase A: gi over K=1536 in 48 chunks of 32, dbuf, 1 barrier/chunk ----
  for (int s = 0; s < NCH; ++s) {
    const int cur = s & 1, nxt = cur ^ 1;
    const bool pf = (s + 1) < NCH;
    if (pf) stageW<EDIM>(wib, (s + 1) * 32, sW[nxt], wave, lane);  // 0-reg prefetch

    bf16x8 af[2];
#pragma unroll
    for (int mt = 0; mt < 2; ++mt) {
      const int m = wm * 32 + mt * 16 + l15;
      af[mt] = *(bf16x8*)(sA[cur] + m * 80 + lq * 16);
    }
#pragma unroll
    for (int g = 0; g < 3; ++g) {
#pragma unroll
      for (int sub = 0; sub < 2; ++sub) {
        const bf16x8 bfr = *(bf16x8*)(sW[cur] + (((g << 3) + sub) << 10) + wrd);
        if (g == 0) {
          accR[0][sub] = MFMA_B16(af[0], bfr, accR[0][sub]);
          accR[1][sub] = MFMA_B16(af[1], bfr, accR[1][sub]);
        } else if (g == 1) {
          accZ[0][sub] = MFMA_B16(af[0], bfr, accZ[0][sub]);
          accZ[1][sub] = MFMA_B16(af[1], bfr, accZ[1][sub]);
        } else {
          accN[0][sub] = MFMA_B16(af[0], bfr, accN[0][sub]);
          accN[1][sub] = MFMA_B16(af[1], bfr, accN[1][sub]);
        }
      }
    }
    if (pf) {  // stage next A slice (+ classifier emb-dot piggyback)
      const int kn = (s + 1) * 32;
      float4 a = make_float4(0.f, 0.f, 0.f, 0.f);
      if (av) a = *(const float4*)(pA + kn);
      const float4 c0 = *(const float4*)(cls_w + kn + aq * 4);
      const float4 c1 = *(const float4*)(cls_w + CDIM + kn + aq * 4);
      lp0 += a.x * c0.x + a.y * c0.y + a.z * c0.z + a.w * c0.w;
      lp1 += a.x * c1.x + a.y * c1.y + a.z * c1.z + a.w * c1.w;
      bf16x4 o = {(bf16)a.x, (bf16)a.y, (bf16)a.z, (bf16)a.w};
      *(bf16x4*)(sA[nxt] + awofs) = o;
    }
    __syncthreads();
  }

  // classifier emb-part: reduce over the 8 threads sharing row ar
  {
    float v0 = lp0, v1 = lp1;
    v0 += __shfl_xor(v0, 1); v0 += __shfl_xor(v0, 2); v0 += __shfl_xor(v0, 4);
    v1 += __shfl_xor(v1, 1); v1 += __shfl_xor(v1, 2); v1 += __shfl_xor(v1, 4);
    if ((lane & 7) == 0) {
      atomicAdd(&sLp[ar][0], v0);
      atomicAdd(&sLp[ar][1], v1);
    }
  }

  // ---- Phase B: gather prev -> sP (proven layout), gh over K=128 ----
  stageW<DDIM>(whb, 0, sW[0], wave, lane);   // phase-A last read was sW[1]
  {
    const int prow = t >> 5;            // 0..15
    const int pc   = t & 31;            // f32 quad: col = pc*4
#pragma unroll
    for (int p = 0; p < 4; ++p) {
      const int r = p * 16 + prow;
      const float4 v = *(const float4*)(mem + (size_t)sIds[r] * DDIM + pc * 4);
      bf16x4 o = {(bf16)v.x, (bf16)v.y, (bf16)v.z, (bf16)v.w};
      *(bf16x4*)(sP + r * 256 + ((pc << 3) ^ ((r & 7) << 4))) = o;
    }
  }
  __syncthreads();

  for (int ks = 0; ks < 4; ++ks) {
    const int cur = ks & 1, nxt = cur ^ 1;
    if (ks + 1 < 4) stageW<DDIM>(whb, (ks + 1) * 32, sW[nxt], wave, lane);
    bf16x8 af[2];
#pragma unroll
    for (int mt = 0; mt < 2; ++mt) {
      const int m = wm * 32 + mt * 16 + l15;
      const int kb = (ks * 32 + lq * 8) << 1;
      af[mt] = *(bf16x8*)(sP + m * 256 + (kb ^ ((m & 7) << 4)));
    }
#pragma unroll
    for (int g = 0; g < 3; ++g) {
#pragma unroll
      for (int sub = 0; sub < 2; ++sub) {
        const bf16x8 bfr = *(bf16x8*)(sW[cur] + (((g << 3) + sub) << 10) + wrd);
        if (g == 0) {
          accR[0][sub] = MFMA_B16(af[0], bfr, accR[0][sub]);
          accR[1][sub] = MFMA_B16(af[1], bfr, accR[1][sub]);
        } else if (g == 1) {
          accZ[0][sub] = MFMA_B16(af[0], bfr, accZ[0][sub]);
          accZ[1][sub] = MFMA_B16(af[1], bfr, accZ[1][sub]);
        } else {
          accH[0][sub] = MFMA_B16(af[0], bfr, accH[0][sub]);
          accH[1][sub] = MFMA_B16(af[1], bfr, accH[1][sub]);
        }
      }
    }
    __syncthreads();
  }

  // ---- Epilogue: gates, scatter new_mem, classifier mem-part ----
  float lpM[8][2];
#pragma unroll
  for (int i = 0; i < 8; ++i) { lpM[i][0] = 0.f; lpM[i][1] = 0.f; }

#pragma unroll
  for (int mt = 0; mt < 2; ++mt) {
#pragma unroll
    for (int sub = 0; sub < 2; ++sub) {
      const int d = wn * 32 + sub * 16 + l15;
      const float cw0 = cls_w[EDIM + d];
      const float cw1 = cls_w[CDIM + EDIM + d];
#pragma unroll
      for (int j = 0; j < 4; ++j) {
        const int m = wm * 32 + mt * 16 + lq * 4 + j;
        const float r = sigf(accR[mt][sub][j]);
        const float z = sigf(accZ[mt][sub][j]);
        const float n = tanhf_fast(accN[mt][sub][j] + r * accH[mt][sub][j]);
        const float pv = mem[(size_t)sIds[m] * DDIM + d];
        const float nv = (1.0f - z) * n + z * pv;
        if (m0 + m < Nrows) omem[(size_t)sIds[m] * DDIM + d] = nv;
        lpM[mt * 4 + j][0] += nv * cw0;
        lpM[mt * 4 + j][1] += nv * cw1;
      }
    }
  }

#pragma unroll
  for (int i = 0; i < 8; ++i) {
#pragma unroll
    for (int c = 0; c < 2; ++c) {
      float v = lpM[i][c];
      v += __shfl_xor(v, 1); v += __shfl_xor(v, 2);
      v += __shfl_xor(v, 4); v += __shfl_xor(v, 8);
      if (l15 == 0) {
        const int m = wm * 32 + (i >> 2) * 16 + lq * 4 + (i & 3);
        atomicAdd(&sLp[m][c], v);
      }
    }
  }
  __syncthreads();

  if (t < 128) {
    const int m = t >> 1, c = t & 1;
    if (m0 + m < Nrows) logits[(size_t)(m0 + m) * 2 + c] = sLp[m][c];
  }
}

extern "C" void kernel_launch(void* const* d_in, const int* in_sizes, int n_in,
                              void* d_out, int out_size, void* d_ws, size_t ws_size,
                              hipStream_t stream) {
  const float* emb   = (const float*)d_in[0];
  const int*   ids   = (const int*)d_in[1];
  const float* mem   = (const float*)d_in[2];
  const float* w_ih  = (const float*)d_in[3];
  const float* w_hh  = (const float*)d_in[4];
  const float* b_ih  = (const float*)d_in[5];
  const float* b_hh  = (const float*)d_in[6];
  const float* cls_w = (const float*)d_in[7];
  const float* cls_b = (const float*)d_in[8];

  const int N    = in_sizes[0] / EDIM;   // 100000
  const int MAXN = in_sizes[2] / DDIM;   // 250000

  float* logits = (float*)d_out;
  float* omem   = (float*)d_out + (size_t)N * 2;
  bf16*  wib    = (bf16*)d_ws;
  bf16*  whb    = wib + 3 * DDIM * EDIM;

  // 1) blanket copy memory -> out (scatter below overwrites active rows)
  hipMemcpyAsync(omem, mem, (size_t)MAXN * DDIM * sizeof(float),
                 hipMemcpyDeviceToDevice, stream);
  // 2) weights to bf16
  const int prep_threads = (3 * DDIM * EDIM + 3 * DDIM * DDIM) / 4;
  prep_convert<<<(prep_threads + 255) / 256, 256, 0, stream>>>(w_ih, w_hh, wib, whb);
  // 3) fused GRU + classifier
  gru_fused<<<(N + TM - 1) / TM, 512, 0, stream>>>(emb, ids, mem, b_ih, b_hh,
                                                   cls_w, cls_b, wib, whb,
                                                   logits, omem, N);
}

// Round 8
// 465.781 us; speedup vs baseline: 1.4185x; 1.1111x over previous
//
#include <hip/hip_runtime.h>
#include <hip/hip_bf16.h>

typedef __bf16 bf16;
typedef __bf16 bf16x4 __attribute__((ext_vector_type(4)));
typedef __bf16 bf16x8 __attribute__((ext_vector_type(8)));
typedef float  f32x4  __attribute__((ext_vector_type(4)));

#define EDIM 1536
#define DDIM 128
#define CDIM 1664   // E + D
#define TM   64
#define NCH  48     // phase A chunks: 1536 / 32

#define MFMA_B16(a, b, c) __builtin_amdgcn_mfma_f32_16x16x32_bf16((a), (b), (c), 0, 0, 0)

__device__ __forceinline__ float sigf(float x) { return 1.0f / (1.0f + __expf(-x)); }
__device__ __forceinline__ float tanhf_fast(float x) { return 2.0f / (1.0f + __expf(-2.0f * x)) - 1.0f; }

__device__ __forceinline__ void glds16(const void* g, void* l) {
  __builtin_amdgcn_global_load_lds(
      (const __attribute__((address_space(1))) unsigned int*)g,
      (__attribute__((address_space(3))) unsigned int*)l, 16, 0, 0);
}

// R4-proven linear staging: slot s holds row s>>2, 16B k-seg s&3.
// Quarter-wave = 4 rows x 64B contiguous (coalesced).
template <int LDA>
__device__ __forceinline__ void stageW(const bf16* __restrict__ w, int k0,
                                       char* dst, int wave, int lane) {
#pragma unroll
  for (int j = 0; j < 3; ++j) {
    const int segbase = j * 512 + wave * 64;     // wave-uniform
    const int s = segbase + lane;                // 0..1535
    const int n = s >> 2;                        // weight row 0..383
    const int q = s & 3;                         // 16B k-seg within chunk
    glds16(w + (size_t)n * LDA + k0 + q * 8, dst + (size_t)segbase * 16);
  }
}

// f32 -> bf16 weight conversion into workspace
__global__ __launch_bounds__(256) void prep_convert(const float* __restrict__ w_ih,
                                                    const float* __restrict__ w_hh,
                                                    bf16* __restrict__ wib,
                                                    bf16* __restrict__ whb) {
  const int i = (blockIdx.x * 256 + threadIdx.x) * 4;
  const int TIH = 3 * DDIM * EDIM;
  const int THH = 3 * DDIM * DDIM;
  if (i < TIH) {
    const float4 v = *(const float4*)(w_ih + i);
    bf16x4 o = {(bf16)v.x, (bf16)v.y, (bf16)v.z, (bf16)v.w};
    *(bf16x4*)(wib + i) = o;
  } else if (i < TIH + THH) {
    const int j = i - TIH;
    const float4 v = *(const float4*)(w_hh + j);
    bf16x4 o = {(bf16)v.x, (bf16)v.y, (bf16)v.z, (bf16)v.w};
    *(bf16x4*)(whb + j) = o;
  }
}

__global__ __launch_bounds__(512, 4) void gru_fused(
    const float* __restrict__ emb, const int* __restrict__ ids,
    const float* __restrict__ mem,
    const float* __restrict__ b_ih, const float* __restrict__ b_hh,
    const float* __restrict__ cls_w, const float* __restrict__ cls_b,
    const bf16* __restrict__ wib, const bf16* __restrict__ whb,
    float* __restrict__ logits, float* __restrict__ omem, int Nrows)
{
  __shared__ char  sW[2][24576];  // W chunk dbuf: 384 rows x 64B, linear (R4)
  __shared__ char  sA[2][5120];   // A slice dbuf: 64 rows x 80B
  __shared__ char  sPC[16384];    // phase A: sC (first 6144B = cls_w bf16 2x1536);
                                  // phase B: prev gathered (64 x 256B swizzled)
  __shared__ float sLp[64][2];
  __shared__ int   sIds[64];

  const int t    = threadIdx.x;
  const int lane = t & 63;
  const int wave = t >> 6;
  const int wm   = wave >> 2;     // 0..1
  const int wn   = wave & 3;      // 0..3
  const int l15  = lane & 15;
  const int lq   = lane >> 4;     // 0..3
  const int m0   = blockIdx.x * TM;

  if (t < 64)  sIds[t] = (m0 + t < Nrows) ? ids[m0 + t] : 0;
  if (t < 128) sLp[t >> 1][t & 1] = cls_b[t & 1];

  // accumulators, bias-initialized (r,z: b_ih+b_hh; n-gate split accN/accH)
  f32x4 accR[2][2], accZ[2][2], accN[2][2], accH[2][2], accC[2];
#pragma unroll
  for (int sub = 0; sub < 2; ++sub) {
    const int nc = wn * 32 + sub * 16 + l15;
    const float br = b_ih[nc] + b_hh[nc];
    const float bz = b_ih[128 + nc] + b_hh[128 + nc];
    const float bn = b_ih[256 + nc];
    const float bh = b_hh[256 + nc];
#pragma unroll
    for (int mt = 0; mt < 2; ++mt) {
      accR[mt][sub] = (f32x4){br, br, br, br};
      accZ[mt][sub] = (f32x4){bz, bz, bz, bz};
      accN[mt][sub] = (f32x4){bn, bn, bn, bn};
      accH[mt][sub] = (f32x4){bh, bh, bh, bh};
    }
  }
  accC[0] = (f32x4){0.f, 0.f, 0.f, 0.f};
  accC[1] = (f32x4){0.f, 0.f, 0.f, 0.f};

  // A staging role: thread t handles row ar = t>>3, f32-quad aq = t&7
  const int  ar = t >> 3;
  const int  aq = t & 7;
  const bool av = (m0 + ar) < Nrows;
  const float* pA = emb + (size_t)(m0 + ar) * EDIM + aq * 4;
  const int  awofs = ar * 80 + aq * 8;
  const float4 fz = make_float4(0.f, 0.f, 0.f, 0.f);
  float4 aA = fz, aB = fz, aC = fz, aD = fz;

  // ---- prologue ----
  stageW<EDIM>(wib, 0, sW[0], wave, lane);
  // cls_w emb-part -> sC (bf16, rows 0..1 x 1536, linear: byte = t*16)
  if (t < 384) {
    const int i = t * 8;                    // bf16 idx 0..3071
    const int r = (i >= 1536) ? 1 : 0;
    const int col = i - r * 1536;
    const float4 u0 = *(const float4*)(cls_w + r * CDIM + col);
    const float4 u1 = *(const float4*)(cls_w + r * CDIM + col + 4);
    bf16x8 o = {(bf16)u0.x, (bf16)u0.y, (bf16)u0.z, (bf16)u0.w,
                (bf16)u1.x, (bf16)u1.y, (bf16)u1.z, (bf16)u1.w};
    *(bf16x8*)(sPC + t * 16) = o;
  }
  { // A slice 0 -> sA[0]; batch-prefetch slices 1..3
    float4 a = av ? *(const float4*)pA : fz;
    bf16x4 o = {(bf16)a.x, (bf16)a.y, (bf16)a.z, (bf16)a.w};
    *(bf16x4*)(sA[0] + awofs) = o;
    if (av) {
      aA = *(const float4*)(pA + 32);
      aB = *(const float4*)(pA + 64);
      aC = *(const float4*)(pA + 96);
    }
  }
  __syncthreads();

  // one chunk body: glds W(c+1), MFMAs on chunk c, ds_write A slice c+1 from AREG
#define BODY(C, AREG) do {                                                     \
    const int cur_ = (C) & 1, nxt_ = cur_ ^ 1;                                 \
    const bool pf_ = (C) + 1 < NCH;                                            \
    if (pf_) stageW<EDIM>(wib, ((C) + 1) * 32, sW[nxt_], wave, lane);          \
    bf16x8 af0_ = *(bf16x8*)(sA[cur_] + (wm * 32 + l15) * 80 + lq * 16);       \
    bf16x8 af1_ = *(bf16x8*)(sA[cur_] + (wm * 32 + 16 + l15) * 80 + lq * 16);  \
    _Pragma("unroll")                                                          \
    for (int g_ = 0; g_ < 3; ++g_) {                                           \
      _Pragma("unroll")                                                        \
      for (int sub_ = 0; sub_ < 2; ++sub_) {                                   \
        const int n_ = g_ * 128 + wn * 32 + sub_ * 16 + l15;                   \
        const bf16x8 bfr_ = *(bf16x8*)(sW[cur_] + n_ * 64 + lq * 16);          \
        if (g_ == 0) {                                                         \
          accR[0][sub_] = MFMA_B16(af0_, bfr_, accR[0][sub_]);                 \
          accR[1][sub_] = MFMA_B16(af1_, bfr_, accR[1][sub_]);                 \
        } else if (g_ == 1) {                                                  \
          accZ[0][sub_] = MFMA_B16(af0_, bfr_, accZ[0][sub_]);                 \
          accZ[1][sub_] = MFMA_B16(af1_, bfr_, accZ[1][sub_]);                 \
        } else {                                                               \
          accN[0][sub_] = MFMA_B16(af0_, bfr_, accN[0][sub_]);                 \
          accN[1][sub_] = MFMA_B16(af1_, bfr_, accN[1][sub_]);                 \
        }                                                                      \
      }                                                                        \
    }                                                                          \
    if (wn == 0) { /* classifier emb-part via MFMA (cols 0,1 at l15<2) */      \
      bf16x8 bc_ = {(bf16)0.f, (bf16)0.f, (bf16)0.f, (bf16)0.f,                \
                    (bf16)0.f, (bf16)0.f, (bf16)0.f, (bf16)0.f};               \
      if (l15 < 2) bc_ = *(bf16x8*)(sPC + l15 * 3072 + (C) * 64 + lq * 16);    \
      accC[0] = MFMA_B16(af0_, bc_, accC[0]);                                  \
      accC[1] = MFMA_B16(af1_, bc_, accC[1]);                                  \
    }                                                                          \
    if (pf_) {                                                                 \
      bf16x4 o_ = {(bf16)(AREG).x, (bf16)(AREG).y,                             \
                   (bf16)(AREG).z, (bf16)(AREG).w};                            \
      *(bf16x4*)(sA[nxt_] + awofs) = o_;                                       \
    }                                                                          \
    __syncthreads();                                                           \
  } while (0)

  // ---- Phase A: 48 chunks, unroll-4, batched A prefetch ----
  for (int S = 0; S < 12; ++S) {
    const int c0 = S * 4;
    if (S < 11 && av) aD = *(const float4*)(pA + (c0 + 4) * 32);
    BODY(c0,     aA);
    BODY(c0 + 1, aB);
    BODY(c0 + 2, aC);
    if (S < 11 && av) {
      aA = *(const float4*)(pA + (c0 + 5) * 32);
      aB = *(const float4*)(pA + (c0 + 6) * 32);
      aC = *(const float4*)(pA + (c0 + 7) * 32);
    }
    BODY(c0 + 3, aD);
  }
#undef BODY

  // ---- Phase B: gather prev -> sPC (proven swizzle), gh over K=128 ----
  stageW<DDIM>(whb, 0, sW[0], wave, lane);
  {
    const int prow = t >> 5;            // 0..15
    const int pc   = t & 31;            // f32 quad: col = pc*4
#pragma unroll
    for (int p = 0; p < 4; ++p) {
      const int r = p * 16 + prow;
      const float4 v = *(const float4*)(mem + (size_t)sIds[r] * DDIM + pc * 4);
      bf16x4 o = {(bf16)v.x, (bf16)v.y, (bf16)v.z, (bf16)v.w};
      *(bf16x4*)(sPC + r * 256 + ((pc << 3) ^ ((r & 7) << 4))) = o;
    }
  }
  __syncthreads();

  for (int ks = 0; ks < 4; ++ks) {
    const int cur = ks & 1, nxt = cur ^ 1;
    if (ks + 1 < 4) stageW<DDIM>(whb, (ks + 1) * 32, sW[nxt], wave, lane);
    bf16x8 af[2];
#pragma unroll
    for (int mt = 0; mt < 2; ++mt) {
      const int m = wm * 32 + mt * 16 + l15;
      const int kb = (ks * 32 + lq * 8) << 1;
      af[mt] = *(bf16x8*)(sPC + m * 256 + (kb ^ ((m & 7) << 4)));
    }
#pragma unroll
    for (int g = 0; g < 3; ++g) {
#pragma unroll
      for (int sub = 0; sub < 2; ++sub) {
        const int n = g * 128 + wn * 32 + sub * 16 + l15;
        const bf16x8 bfr = *(bf16x8*)(sW[cur] + n * 64 + lq * 16);
        if (g == 0) {
          accR[0][sub] = MFMA_B16(af[0], bfr, accR[0][sub]);
          accR[1][sub] = MFMA_B16(af[1], bfr, accR[1][sub]);
        } else if (g == 1) {
          accZ[0][sub] = MFMA_B16(af[0], bfr, accZ[0][sub]);
          accZ[1][sub] = MFMA_B16(af[1], bfr, accZ[1][sub]);
        } else {
          accH[0][sub] = MFMA_B16(af[0], bfr, accH[0][sub]);
          accH[1][sub] = MFMA_B16(af[1], bfr, accH[1][sub]);
        }
      }
    }
    __syncthreads();
  }

  // ---- Epilogue: gates, scatter new_mem, classifier ----
  float lpM[8][2];
#pragma unroll
  for (int i = 0; i < 8; ++i) { lpM[i][0] = 0.f; lpM[i][1] = 0.f; }

#pragma unroll
  for (int mt = 0; mt < 2; ++mt) {
#pragma unroll
    for (int sub = 0; sub < 2; ++sub) {
      const int d = wn * 32 + sub * 16 + l15;
      const float cw0 = cls_w[EDIM + d];
      const float cw1 = cls_w[CDIM + EDIM + d];
#pragma unroll
      for (int j = 0; j < 4; ++j) {
        const int m = wm * 32 + mt * 16 + lq * 4 + j;
        const float r = sigf(accR[mt][sub][j]);
        const float z = sigf(accZ[mt][sub][j]);
        const float n = tanhf_fast(accN[mt][sub][j] + r * accH[mt][sub][j]);
        const float pv = mem[(size_t)sIds[m] * DDIM + d];
        const float nv = (1.0f - z) * n + z * pv;
        if (m0 + m < Nrows) omem[(size_t)sIds[m] * DDIM + d] = nv;
        lpM[mt * 4 + j][0] += nv * cw0;
        lpM[mt * 4 + j][1] += nv * cw1;
      }
    }
  }

  // classifier emb-part from accC (wave wn==0, cols l15<2)
  if (wn == 0 && l15 < 2) {
#pragma unroll
    for (int mt = 0; mt < 2; ++mt)
#pragma unroll
      for (int j = 0; j < 4; ++j)
        atomicAdd(&sLp[wm * 32 + mt * 16 + lq * 4 + j][l15], accC[mt][j]);
  }

#pragma unroll
  for (int i = 0; i < 8; ++i) {
#pragma unroll
    for (int c = 0; c < 2; ++c) {
      float v = lpM[i][c];
      v += __shfl_xor(v, 1); v += __shfl_xor(v, 2);
      v += __shfl_xor(v, 4); v += __shfl_xor(v, 8);
      if (l15 == 0) {
        const int m = wm * 32 + (i >> 2) * 16 + lq * 4 + (i & 3);
        atomicAdd(&sLp[m][c], v);
      }
    }
  }
  __syncthreads();

  if (t < 128) {
    const int m = t >> 1, c = t & 1;
    if (m0 + m < Nrows) logits[(size_t)(m0 + m) * 2 + c] = sLp[m][c];
  }
}

extern "C" void kernel_launch(void* const* d_in, const int* in_sizes, int n_in,
                              void* d_out, int out_size, void* d_ws, size_t ws_size,
                              hipStream_t stream) {
  const float* emb   = (const float*)d_in[0];
  const int*   ids   = (const int*)d_in[1];
  const float* mem   = (const float*)d_in[2];
  const float* w_ih  = (const float*)d_in[3];
  const float* w_hh  = (const float*)d_in[4];
  const float* b_ih  = (const float*)d_in[5];
  const float* b_hh  = (const float*)d_in[6];
  const float* cls_w = (const float*)d_in[7];
  const float* cls_b = (const float*)d_in[8];

  const int N    = in_sizes[0] / EDIM;   // 100000
  const int MAXN = in_sizes[2] / DDIM;   // 250000

  float* logits = (float*)d_out;
  float* omem   = (float*)d_out + (size_t)N * 2;
  bf16*  wib    = (bf16*)d_ws;
  bf16*  whb    = wib + 3 * DDIM * EDIM;

  hipMemcpyAsync(omem, mem, (size_t)MAXN * DDIM * sizeof(float),
                 hipMemcpyDeviceToDevice, stream);
  const int prep_threads = (3 * DDIM * EDIM + 3 * DDIM * DDIM) / 4;
  prep_convert<<<(prep_threads + 255) / 256, 256, 0, stream>>>(w_ih, w_hh, wib, whb);
  gru_fused<<<(N + TM - 1) / TM, 512, 0, stream>>>(emb, ids, mem, b_ih, b_hh,
                                                   cls_w, cls_b, wib, whb,
                                                   logits, omem, N);
}